// Round 1
// baseline (435.065 us; speedup 1.0000x reference)
//
#include <hip/hip_runtime.h>
#include <cstdint>
#include <cstddef>

// ---------- common ----------
typedef __bf16 bf16x8 __attribute__((ext_vector_type(8)));
typedef float  f32x4  __attribute__((ext_vector_type(4)));

__device__ __forceinline__ uint16_t f2bf(float f) {
  uint32_t u = __float_as_uint(f);
  u += 0x7fffu + ((u >> 16) & 1u);          // round-to-nearest-even
  return (uint16_t)(u >> 16);
}

__device__ __forceinline__ f32x4 mfma16(bf16x8 a, bf16x8 b, f32x4 c) {
  return __builtin_amdgcn_mfma_f32_16x16x32_bf16(a, b, c, 0, 0, 0);
}

#define GLD_TO_LDS16(gptr, lptr)                                                   \
  __builtin_amdgcn_global_load_lds(                                                \
      (const __attribute__((address_space(1))) void*)(gptr),                       \
      (__attribute__((address_space(3))) void*)(lptr), 16, 0, 0)

// ---------- fp32 -> bf16 cast, 4 elems/thread ----------
__global__ void cvt_kernel(const float* __restrict__ in, uint16_t* __restrict__ out, int n4) {
  int i = blockIdx.x * blockDim.x + threadIdx.x;
  if (i < n4) {
    float4 v = ((const float4*)in)[i];
    ushort4 o;
    o.x = f2bf(v.x); o.y = f2bf(v.y); o.z = f2bf(v.z); o.w = f2bf(v.w);
    ((ushort4*)out)[i] = o;
  }
}

// ---------- C[M,N] = A[M,K] @ B[N,K]^T, bf16 in, fp32 acc ----------
// MODE 0: Q proj  -> o16a[b,h,t,d] = (c+bias)*0.125
// MODE 1: KV proj -> K: o16a[b,h,s,d] ; V: o16b[b,h,d,s] (transposed)
// MODE 2: out proj-> o32[i,f] = c+bias (fp32)
template <int MODE>
__global__ __launch_bounds__(256)
void gemm_bt(const uint16_t* __restrict__ A, const uint16_t* __restrict__ B,
             const float* __restrict__ bias, uint16_t* __restrict__ o16a,
             uint16_t* __restrict__ o16b, float* __restrict__ o32,
             int M, int N, int K) {
  __shared__ __align__(16) uint16_t As[128 * 32];
  __shared__ __align__(16) uint16_t Bs[128 * 32];
  const int tid  = threadIdx.x;
  const int wave = tid >> 6, lane = tid & 63;
  const int quad = lane >> 4, l16 = lane & 15;
  const int nt = N >> 7;
  const int bm = blockIdx.x / nt, bn = blockIdx.x % nt;
  const int wm = (wave >> 1) << 6, wn = (wave & 1) << 6;

  f32x4 acc[4][4] = {};

  for (int k0 = 0; k0 < K; k0 += 32) {
    __syncthreads();
#pragma unroll
    for (int j = 0; j < 2; j++) {
      int c   = wave * 128 + j * 64 + lane;   // chunk id, 16B each
      int row = c >> 2, kc = c & 3;
      const uint16_t* ga = A + (size_t)(bm * 128 + row) * K + k0 + kc * 8;
      GLD_TO_LDS16(ga, As + (size_t)(wave * 128 + j * 64) * 8);
      const uint16_t* gb = B + (size_t)(bn * 128 + row) * K + k0 + kc * 8;
      GLD_TO_LDS16(gb, Bs + (size_t)(wave * 128 + j * 64) * 8);
    }
    __syncthreads();

    bf16x8 af[4], bfr[4];
#pragma unroll
    for (int i = 0; i < 4; i++) {
      af[i]  = *(const bf16x8*)(As + (wm + i * 16 + l16) * 32 + quad * 8);
      bfr[i] = *(const bf16x8*)(Bs + (wn + i * 16 + l16) * 32 + quad * 8);
    }
#pragma unroll
    for (int mi = 0; mi < 4; mi++)
#pragma unroll
      for (int ni = 0; ni < 4; ni++)
        acc[mi][ni] = mfma16(af[mi], bfr[ni], acc[mi][ni]);
  }

  // epilogue: C row = quad*4+reg, col = l16 (verified m89/m91 layout)
#pragma unroll
  for (int mi = 0; mi < 4; mi++)
#pragma unroll
    for (int ni = 0; ni < 4; ni++)
#pragma unroll
      for (int r = 0; r < 4; r++) {
        int gi = bm * 128 + wm + mi * 16 + quad * 4 + r;  // row in X = t*4+b
        int gf = bn * 128 + wn + ni * 16 + l16;           // feature
        float c = acc[mi][ni][r] + bias[gf];
        if (MODE == 0) {
          c *= 0.125f;  // HD^-0.5
          int t = gi >> 2, b = gi & 3, h = gf >> 6, d = gf & 63;
          o16a[((((size_t)b * 16 + h) * 1024 + t) << 6) + d] = f2bf(c);
        } else if (MODE == 1) {
          int s = gi >> 2, b = gi & 3;
          if (gf < 1024) {
            int h = gf >> 6, d = gf & 63;
            o16a[((((size_t)b * 16 + h) * 1024 + s) << 6) + d] = f2bf(c);
          } else {
            int fv = gf - 1024, h = fv >> 6, d = fv & 63;
            o16b[((((size_t)b * 16 + h) * 64 + d) << 10) + s] = f2bf(c);
          }
        } else {
          o32[(size_t)gi * 1024 + gf] = c;
        }
      }
}

// ---------- attention: block = (b, 16-row t-tile), loops 16 heads ----------
// qb: (b,h,t,d) bf16 (pre-scaled), kb: (b,h,s,d) bf16, vtb: (b,h,d,s) bf16
// hard: (b,t,s) fp32 {0,1}; attn_out: (t,b,h*64+d) bf16; avg_out: (b,t,s) fp32
__global__ __launch_bounds__(256)
void attn_kernel(const uint16_t* __restrict__ qb, const uint16_t* __restrict__ kb,
                 const uint16_t* __restrict__ vtb, const float* __restrict__ hard,
                 uint16_t* __restrict__ attn_out, float* __restrict__ avg_out) {
  __shared__ __align__(16) uint16_t P[16 * 1032];  // padded: stride 1032 elems
  __shared__ float redM[4][16];
  __shared__ float redS[4][16];

  const int b  = blockIdx.x >> 6;
  const int t0 = (blockIdx.x & 63) << 4;
  const int tid = threadIdx.x, wave = tid >> 6, lane = tid & 63;
  const int quad = lane >> 4, l16 = lane & 15;
  const int tl = quad * 4;              // this lane's 4 C-rows: tl..tl+3
  const int sbase = wave * 256 + l16;   // this lane's s column base

  // hard mask -> 64-bit register mask, bit n*4+r <-> (t=t0+tl+r, s=sbase+n*16)
  unsigned long long hbits = 0ull;
#pragma unroll
  for (int n = 0; n < 16; n++)
#pragma unroll
    for (int r = 0; r < 4; r++) {
      float hv = hard[(size_t)(b * 1024 + t0 + tl + r) * 1024 + sbase + n * 16];
      if (hv != 0.0f) hbits |= (1ull << (n * 4 + r));
    }

  float avg[16][4] = {};

  for (int h = 0; h < 16; h++) {
    const size_t bh = (size_t)(b * 16 + h);

    // Q A-frags (m = l16, k = quad*8+j), k-chunks 0..31 / 32..63
    const uint16_t* qrow = qb + ((bh << 10) + t0 + l16) * 64;
    bf16x8 aq0 = *(const bf16x8*)(qrow + quad * 8);
    bf16x8 aq1 = *(const bf16x8*)(qrow + 32 + quad * 8);

    // S = Q K^T : wave covers s in [wave*256, wave*256+256)
    f32x4 sreg[16];
#pragma unroll
    for (int n = 0; n < 16; n++) {
      const uint16_t* krow = kb + ((bh << 10) + wave * 256 + n * 16 + l16) * 64;
      bf16x8 bk0 = *(const bf16x8*)(krow + quad * 8);
      bf16x8 bk1 = *(const bf16x8*)(krow + 32 + quad * 8);
      f32x4 c = {};
      c = mfma16(aq0, bk0, c);
      c = mfma16(aq1, bk1, c);
      sreg[n] = c;
    }

    // row max (in-regs -> quad shuffle -> cross-wave LDS)
    float mx[4];
#pragma unroll
    for (int r = 0; r < 4; r++) {
      float v = sreg[0][r];
#pragma unroll
      for (int n = 1; n < 16; n++) v = fmaxf(v, sreg[n][r]);
#pragma unroll
      for (int off = 1; off < 16; off <<= 1) v = fmaxf(v, __shfl_xor(v, off));
      mx[r] = v;
    }
    if (l16 == 0) {
#pragma unroll
      for (int r = 0; r < 4; r++) redM[wave][tl + r] = mx[r];
    }
    __syncthreads();
    float m[4];
#pragma unroll
    for (int r = 0; r < 4; r++)
      m[r] = fmaxf(fmaxf(redM[0][tl + r], redM[1][tl + r]),
                   fmaxf(redM[2][tl + r], redM[3][tl + r]));

    // exp + row sum
    float sm[4];
#pragma unroll
    for (int r = 0; r < 4; r++) {
      float s = 0.f;
#pragma unroll
      for (int n = 0; n < 16; n++) {
        float e = __expf(sreg[n][r] - m[r]);
        sreg[n][r] = e;
        s += e;
      }
#pragma unroll
      for (int off = 1; off < 16; off <<= 1) s += __shfl_xor(s, off);
      sm[r] = s;
    }
    if (l16 == 0) {
#pragma unroll
      for (int r = 0; r < 4; r++) redS[wave][tl + r] = sm[r];
    }
    __syncthreads();
    float rl[4];
#pragma unroll
    for (int r = 0; r < 4; r++) {
      float l = redS[0][tl + r] + redS[1][tl + r] + redS[2][tl + r] + redS[3][tl + r];
      rl[r] = 1.0f / l;
    }

    // p = softmax * hard ; accumulate head-average ; stash P (bf16) for PV
#pragma unroll
    for (int n = 0; n < 16; n++)
#pragma unroll
      for (int r = 0; r < 4; r++) {
        float p = sreg[n][r] * rl[r];
        if (!((hbits >> (n * 4 + r)) & 1ull)) p = 0.f;
        avg[n][r] += p;
        P[(tl + r) * 1032 + sbase + n * 16] = f2bf(p);
      }
    __syncthreads();

    // O = P @ V : wave covers d in [wave*16, wave*16+16); 4 indep acc chains
    f32x4 oa[4] = {};
#pragma unroll
    for (int kc = 0; kc < 32; kc++) {
      bf16x8 ap = *(const bf16x8*)(P + l16 * 1032 + kc * 32 + quad * 8);
      bf16x8 bv = *(const bf16x8*)(vtb + ((bh << 6) + wave * 16 + l16) * 1024 +
                                   kc * 32 + quad * 8);
      oa[kc & 3] = mfma16(ap, bv, oa[kc & 3]);
    }
#pragma unroll
    for (int r = 0; r < 4; r++) {
      float o = oa[0][r] + oa[1][r] + oa[2][r] + oa[3][r];
      attn_out[((size_t)(t0 + tl + r) * 4 + b) * 1024 + h * 64 + wave * 16 + l16] =
          f2bf(o);
    }
    __syncthreads();  // protect P before next head overwrites
  }

  // write head-averaged attention
#pragma unroll
  for (int n = 0; n < 16; n++)
#pragma unroll
    for (int r = 0; r < 4; r++)
      avg_out[(size_t)(b * 1024 + t0 + tl + r) * 1024 + sbase + n * 16] =
          avg[n][r] * 0.0625f;
}

// ---------- launch ----------
extern "C" void kernel_launch(void* const* d_in, const int* in_sizes, int n_in,
                              void* d_out, int out_size, void* d_ws, size_t ws_size,
                              hipStream_t stream) {
  const float* query = (const float*)d_in[0];
  const float* key   = (const float*)d_in[1];
  const float* hard  = (const float*)d_in[2];
  const float* ipw   = (const float*)d_in[3];
  const float* ipb   = (const float*)d_in[4];
  const float* opw   = (const float*)d_in[5];
  const float* opb   = (const float*)d_in[6];

  char* ws = (char*)d_ws;
  const size_t MB = 1ull << 20;
  uint16_t* Xq  = (uint16_t*)(ws + 0);        // 8 MB (reused as attn_out)
  uint16_t* Xk  = (uint16_t*)(ws + 8 * MB);   // 8 MB
  uint16_t* Wb  = (uint16_t*)(ws + 16 * MB);  // 6 MB (3072x1024)
  uint16_t* Wob = (uint16_t*)(ws + 22 * MB);  // 2 MB
  uint16_t* Qb  = (uint16_t*)(ws + 24 * MB);  // 8 MB (b,h,t,d)
  uint16_t* Kb  = (uint16_t*)(ws + 32 * MB);  // 8 MB (b,h,s,d)
  uint16_t* Vt  = (uint16_t*)(ws + 40 * MB);  // 8 MB (b,h,d,s)
  uint16_t* AO  = Xq;                         // alias: Xq dead after gemm<0>

  float* out = (float*)d_out;
  float* avg = out + 4194304;

  cvt_kernel<<<4096, 256, 0, stream>>>(query, Xq, 1048576);
  cvt_kernel<<<4096, 256, 0, stream>>>(key, Xk, 1048576);
  cvt_kernel<<<3072, 256, 0, stream>>>(ipw, Wb, 786432);
  cvt_kernel<<<1024, 256, 0, stream>>>(opw, Wob, 262144);

  // Q = query @ Wq^T, scaled, -> (b,h,t,d)
  gemm_bt<0><<<256, 256, 0, stream>>>(Xq, Wb, ipb, Qb, nullptr, nullptr,
                                      4096, 1024, 1024);
  // KV = key @ Wkv^T -> K (b,h,s,d), V^T (b,h,d,s)
  gemm_bt<1><<<512, 256, 0, stream>>>(Xk, Wb + 1024 * 1024, ipb + 1024, Kb, Vt,
                                      nullptr, 4096, 2048, 1024);
  // attention + head-avg
  attn_kernel<<<256, 256, 0, stream>>>(Qb, Kb, Vt, hard, AO, avg);
  // out = AO @ Wo^T + bias (fp32 direct to d_out)
  gemm_bt<2><<<256, 256, 0, stream>>>(AO, Wob, opb, nullptr, nullptr, out,
                                      4096, 1024, 1024);
}

// Round 2
// 412.787 us; speedup vs baseline: 1.0540x; 1.0540x over previous
//
#include <hip/hip_runtime.h>
#include <cstdint>
#include <cstddef>

// ---------- common ----------
typedef __bf16 bf16x8 __attribute__((ext_vector_type(8)));
typedef float  f32x4  __attribute__((ext_vector_type(4)));

__device__ __forceinline__ uint16_t f2bf(float f) {
  uint32_t u = __float_as_uint(f);
  u += 0x7fffu + ((u >> 16) & 1u);          // round-to-nearest-even
  return (uint16_t)(u >> 16);
}

__device__ __forceinline__ f32x4 mfma16(bf16x8 a, bf16x8 b, f32x4 c) {
  return __builtin_amdgcn_mfma_f32_16x16x32_bf16(a, b, c, 0, 0, 0);
}

#define GLD_TO_LDS16(gptr, lptr)                                                   \
  __builtin_amdgcn_global_load_lds(                                                \
      (const __attribute__((address_space(1))) void*)(gptr),                       \
      (__attribute__((address_space(3))) void*)(lptr), 16, 0, 0)

// ---------- fused fp32 -> bf16 cast of all 4 tensors ----------
// f4 ranges: q [0,1048576) k [..2097152) ipw [..2883584) opw [..3145728)
__global__ void cvt_all(const float* __restrict__ q, const float* __restrict__ k,
                        const float* __restrict__ w, const float* __restrict__ wo,
                        uint16_t* __restrict__ Xq, uint16_t* __restrict__ Xk,
                        uint16_t* __restrict__ Wb, uint16_t* __restrict__ Wob) {
  int i = blockIdx.x * blockDim.x + threadIdx.x;
  const float* src;
  uint16_t* dst;
  int off;
  if (i < 1048576)      { src = q;  dst = Xq;  off = i; }
  else if (i < 2097152) { src = k;  dst = Xk;  off = i - 1048576; }
  else if (i < 2883584) { src = w;  dst = Wb;  off = i - 2097152; }
  else                  { src = wo; dst = Wob; off = i - 2883584; }
  float4 v = ((const float4*)src)[off];
  ushort4 o;
  o.x = f2bf(v.x); o.y = f2bf(v.y); o.z = f2bf(v.z); o.w = f2bf(v.w);
  ((ushort4*)dst)[off] = o;
}

// ---------- fused Q + KV projection, 128x128 tiles, grid 768 (3 blk/CU) ----
// bid<256: Q = Xq @ Wq^T  -> Qb[b,h,t,d] = (c+bias)*0.125
// bid>=256: KV = Xk @ Wkv^T -> K: Kb[b,h,s,d]; V: Vt[b,h,d,s] (transposed)
__global__ __launch_bounds__(256)
void gemm_qkv(const uint16_t* __restrict__ Xq, const uint16_t* __restrict__ Xk,
              const uint16_t* __restrict__ Wb, const float* __restrict__ ipb,
              uint16_t* __restrict__ Qb, uint16_t* __restrict__ Kb,
              uint16_t* __restrict__ Vt) {
  __shared__ __align__(16) uint16_t As[128 * 32];
  __shared__ __align__(16) uint16_t Bs[128 * 32];
  const int tid  = threadIdx.x;
  const int wave = tid >> 6, lane = tid & 63;
  const int quad = lane >> 4, l16 = lane & 15;

  const int bid = blockIdx.x;
  const uint16_t *A, *B;
  const float* bias;
  int bm, bn, mode;
  if (bid < 256) {
    mode = 0; A = Xq; B = Wb; bias = ipb;
    bm = bid >> 3; bn = bid & 7;
  } else {
    mode = 1; A = Xk; B = Wb + (1 << 20); bias = ipb + 1024;
    int t = bid - 256; bm = t >> 4; bn = t & 15;
  }
  const int wm = (wave >> 1) << 6, wn = (wave & 1) << 6;
  const int K = 1024;

  f32x4 acc[4][4] = {};

  for (int k0 = 0; k0 < K; k0 += 32) {
    __syncthreads();
#pragma unroll
    for (int j = 0; j < 2; j++) {
      int c   = wave * 128 + j * 64 + lane;
      int row = c >> 2, kc = c & 3;
      const uint16_t* ga = A + (size_t)(bm * 128 + row) * K + k0 + kc * 8;
      GLD_TO_LDS16(ga, As + (size_t)(wave * 128 + j * 64) * 8);
      const uint16_t* gb = B + (size_t)(bn * 128 + row) * K + k0 + kc * 8;
      GLD_TO_LDS16(gb, Bs + (size_t)(wave * 128 + j * 64) * 8);
    }
    __syncthreads();

    bf16x8 af[4], bfr[4];
#pragma unroll
    for (int i = 0; i < 4; i++) {
      af[i]  = *(const bf16x8*)(As + (wm + i * 16 + l16) * 32 + quad * 8);
      bfr[i] = *(const bf16x8*)(Bs + (wn + i * 16 + l16) * 32 + quad * 8);
    }
#pragma unroll
    for (int mi = 0; mi < 4; mi++)
#pragma unroll
      for (int ni = 0; ni < 4; ni++)
        acc[mi][ni] = mfma16(af[mi], bfr[ni], acc[mi][ni]);
  }

#pragma unroll
  for (int mi = 0; mi < 4; mi++)
#pragma unroll
    for (int ni = 0; ni < 4; ni++)
#pragma unroll
      for (int r = 0; r < 4; r++) {
        int gi = bm * 128 + wm + mi * 16 + quad * 4 + r;  // row = t*4+b
        int gf = bn * 128 + wn + ni * 16 + l16;
        float c = acc[mi][ni][r] + bias[gf];
        if (mode == 0) {
          c *= 0.125f;  // HD^-0.5
          int t = gi >> 2, b = gi & 3, h = gf >> 6, d = gf & 63;
          Qb[((((size_t)b * 16 + h) * 1024 + t) << 6) + d] = f2bf(c);
        } else {
          int s = gi >> 2, b = gi & 3;
          if (gf < 1024) {
            int h = gf >> 6, d = gf & 63;
            Kb[((((size_t)b * 16 + h) * 1024 + s) << 6) + d] = f2bf(c);
          } else {
            int fv = gf - 1024, h = fv >> 6, d = fv & 63;
            Vt[((((size_t)b * 16 + h) * 64 + d) << 10) + s] = f2bf(c);
          }
        }
      }
}

// ---------- out-projection, 64x128 tiles, grid 512 (2 blk/CU) ----------
__global__ __launch_bounds__(256)
void gemm_out(const uint16_t* __restrict__ A, const uint16_t* __restrict__ B,
              const float* __restrict__ bias, float* __restrict__ o32) {
  __shared__ __align__(16) uint16_t As[64 * 32];
  __shared__ __align__(16) uint16_t Bs[128 * 32];
  const int tid  = threadIdx.x;
  const int wave = tid >> 6, lane = tid & 63;
  const int quad = lane >> 4, l16 = lane & 15;
  const int bm = blockIdx.x >> 3, bn = blockIdx.x & 7;  // 64 x 8 tiles
  const int wm = (wave >> 1) << 5, wn = (wave & 1) << 6;
  const int K = 1024;

  f32x4 acc[2][4] = {};

  for (int k0 = 0; k0 < K; k0 += 32) {
    __syncthreads();
    {
      int c   = wave * 64 + lane;       // A: 256 chunks, 1/thread
      int row = c >> 2, kc = c & 3;
      const uint16_t* ga = A + (size_t)(bm * 64 + row) * K + k0 + kc * 8;
      GLD_TO_LDS16(ga, As + (size_t)(wave * 64) * 8);
    }
#pragma unroll
    for (int j = 0; j < 2; j++) {       // B: 512 chunks, 2/thread
      int c   = wave * 128 + j * 64 + lane;
      int row = c >> 2, kc = c & 3;
      const uint16_t* gb = B + (size_t)(bn * 128 + row) * K + k0 + kc * 8;
      GLD_TO_LDS16(gb, Bs + (size_t)(wave * 128 + j * 64) * 8);
    }
    __syncthreads();

    bf16x8 af[2], bfr[4];
#pragma unroll
    for (int i = 0; i < 2; i++)
      af[i] = *(const bf16x8*)(As + (wm + i * 16 + l16) * 32 + quad * 8);
#pragma unroll
    for (int i = 0; i < 4; i++)
      bfr[i] = *(const bf16x8*)(Bs + (wn + i * 16 + l16) * 32 + quad * 8);
#pragma unroll
    for (int mi = 0; mi < 2; mi++)
#pragma unroll
      for (int ni = 0; ni < 4; ni++)
        acc[mi][ni] = mfma16(af[mi], bfr[ni], acc[mi][ni]);
  }

#pragma unroll
  for (int mi = 0; mi < 2; mi++)
#pragma unroll
    for (int ni = 0; ni < 4; ni++)
#pragma unroll
      for (int r = 0; r < 4; r++) {
        int gi = bm * 64 + wm + mi * 16 + quad * 4 + r;
        int gf = bn * 128 + wn + ni * 16 + l16;
        o32[(size_t)gi * 1024 + gf] = acc[mi][ni][r] + bias[gf];
      }
}

// ---------- attention: block = (b, t-tile16, head-group-of-4) ----------
// grid 1024 = 4b x 4hg x 64tt ; 4 blocks/CU target.
// qb (b,h,t,d) pre-scaled; kb (b,h,s,d); vtb (b,h,d,s); hard (b,t,s) fp32
// attn_out (t, b, h*64+d) bf16; avg_out (b,t,s) fp32 (pre-zeroed, atomicAdd)
__global__ __launch_bounds__(256, 4)
void attn_kernel(const uint16_t* __restrict__ qb, const uint16_t* __restrict__ kb,
                 const uint16_t* __restrict__ vtb, const float* __restrict__ hard,
                 uint16_t* __restrict__ attn_out, float* __restrict__ avg_out) {
  __shared__ __align__(16) uint16_t P[16 * 1032];  // masked unnormalized exp
  __shared__ float redS[4][16];

  const int bid = blockIdx.x;
  const int b  = bid >> 8;
  const int hg = (bid >> 6) & 3;
  const int t0 = (bid & 63) << 4;
  const int tid = threadIdx.x, wave = tid >> 6, lane = tid & 63;
  const int quad = lane >> 4, l16 = lane & 15;
  const int tl = quad * 4;              // this lane's 4 C-rows: tl..tl+3
  const int sbase = wave * 256 + l16;   // this lane's s column base

  // hard mask -> 64-bit register mask, bit n*4+r <-> (t=t0+tl+r, s=sbase+n*16)
  unsigned long long hbits = 0ull;
#pragma unroll
  for (int n = 0; n < 16; n++)
#pragma unroll
    for (int r = 0; r < 4; r++) {
      float hv = hard[(size_t)(b * 1024 + t0 + tl + r) * 1024 + sbase + n * 16];
      if (hv != 0.0f) hbits |= (1ull << (n * 4 + r));
    }

  float avg[16][4] = {};

  for (int hh = 0; hh < 4; hh++) {
    const int h = hg * 4 + hh;
    const size_t bh = (size_t)(b * 16 + h);

    // Q A-frags (m = l16, k = quad*8+j)
    const uint16_t* qrow = qb + ((bh << 10) + t0 + l16) * 64;
    bf16x8 aq0 = *(const bf16x8*)(qrow + quad * 8);
    bf16x8 aq1 = *(const bf16x8*)(qrow + 32 + quad * 8);

    // S = Q K^T : wave covers s in [wave*256, wave*256+256)
    f32x4 sreg[16];
#pragma unroll
    for (int n = 0; n < 16; n++) {
      const uint16_t* krow = kb + ((bh << 10) + wave * 256 + n * 16 + l16) * 64;
      bf16x8 bk0 = *(const bf16x8*)(krow + quad * 8);
      bf16x8 bk1 = *(const bf16x8*)(krow + 32 + quad * 8);
      f32x4 c = {};
      c = mfma16(aq0, bk0, c);
      c = mfma16(aq1, bk1, c);
      sreg[n] = c;
    }

    // exp (no max-subtract: |score| <~ 4, safe in fp32), row-sum of UNMASKED e,
    // apply hard mask, stash masked e in P (bf16) and keep in sreg
    float sm[4] = {0.f, 0.f, 0.f, 0.f};
#pragma unroll
    for (int n = 0; n < 16; n++)
#pragma unroll
      for (int r = 0; r < 4; r++) {
        float e = __expf(sreg[n][r]);
        sm[r] += e;
        float em = ((hbits >> (n * 4 + r)) & 1ull) ? e : 0.f;
        sreg[n][r] = em;
        P[(tl + r) * 1032 + sbase + n * 16] = f2bf(em);
      }
#pragma unroll
    for (int r = 0; r < 4; r++) {
      float s = sm[r];
#pragma unroll
      for (int off = 1; off < 16; off <<= 1) s += __shfl_xor(s, off);
      if (l16 == 0) redS[wave][tl + r] = s;
    }
    __syncthreads();

    float rl[4];
#pragma unroll
    for (int r = 0; r < 4; r++)
      rl[r] = 1.0f / (redS[0][tl + r] + redS[1][tl + r] +
                      redS[2][tl + r] + redS[3][tl + r]);

    // head-average accumulation (normalized masked p)
#pragma unroll
    for (int n = 0; n < 16; n++)
#pragma unroll
      for (int r = 0; r < 4; r++) avg[n][r] += sreg[n][r] * rl[r];

    // O = (P @ V) * rl : wave covers d in [wave*16, wave*16+16)
    f32x4 oa[4] = {};
#pragma unroll
    for (int kc = 0; kc < 32; kc++) {
      bf16x8 ap = *(const bf16x8*)(P + l16 * 1032 + kc * 32 + quad * 8);
      bf16x8 bv = *(const bf16x8*)(vtb + ((bh << 6) + wave * 16 + l16) * 1024 +
                                   kc * 32 + quad * 8);
      oa[kc & 3] = mfma16(ap, bv, oa[kc & 3]);
    }
#pragma unroll
    for (int r = 0; r < 4; r++) {
      float o = (oa[0][r] + oa[1][r] + oa[2][r] + oa[3][r]) * rl[r];
      attn_out[((size_t)(t0 + tl + r) * 4 + b) * 1024 + h * 64 + wave * 16 + l16] =
          f2bf(o);
    }
    __syncthreads();  // protect P/redS before next head overwrites
  }

  // combine head-group average into global avg (4-way contention only)
#pragma unroll
  for (int n = 0; n < 16; n++)
#pragma unroll
    for (int r = 0; r < 4; r++)
      atomicAdd(&avg_out[(size_t)(b * 1024 + t0 + tl + r) * 1024 + sbase + n * 16],
                avg[n][r] * 0.0625f);
}

// ---------- launch ----------
extern "C" void kernel_launch(void* const* d_in, const int* in_sizes, int n_in,
                              void* d_out, int out_size, void* d_ws, size_t ws_size,
                              hipStream_t stream) {
  const float* query = (const float*)d_in[0];
  const float* key   = (const float*)d_in[1];
  const float* hard  = (const float*)d_in[2];
  const float* ipw   = (const float*)d_in[3];
  const float* ipb   = (const float*)d_in[4];
  const float* opw   = (const float*)d_in[5];
  const float* opb   = (const float*)d_in[6];

  char* ws = (char*)d_ws;
  const size_t MB = 1ull << 20;
  uint16_t* Xq  = (uint16_t*)(ws + 0);        // 8 MB (reused as attn_out)
  uint16_t* Xk  = (uint16_t*)(ws + 8 * MB);   // 8 MB
  uint16_t* Wb  = (uint16_t*)(ws + 16 * MB);  // 6 MB (3072x1024)
  uint16_t* Wob = (uint16_t*)(ws + 22 * MB);  // 2 MB
  uint16_t* Qb  = (uint16_t*)(ws + 24 * MB);  // 8 MB (b,h,t,d)
  uint16_t* Kb  = (uint16_t*)(ws + 32 * MB);  // 8 MB (b,h,s,d)
  uint16_t* Vt  = (uint16_t*)(ws + 40 * MB);  // 8 MB (b,h,d,s)
  uint16_t* AO  = Xq;                         // alias: Xq dead after gemm_qkv

  float* out = (float*)d_out;
  float* avg = out + 4194304;

  hipMemsetAsync(avg, 0, 4194304 * sizeof(float), stream);

  cvt_all<<<12288, 256, 0, stream>>>(query, key, ipw, opw, Xq, Xk, Wb, Wob);

  // fused Q-proj (256 blocks) + KV-proj (512 blocks)
  gemm_qkv<<<768, 256, 0, stream>>>(Xq, Xk, Wb, ipb, Qb, Kb, Vt);

  // attention + head-avg: 4 head-groups x 4 b x 64 t-tiles
  attn_kernel<<<1024, 256, 0, stream>>>(Qb, Kb, Vt, hard, AO, avg);

  // out = AO @ Wo^T + bias (fp32 direct to d_out)
  gemm_out<<<512, 256, 0, stream>>>(AO, Wob, opb, out);
}

// Round 3
// 328.993 us; speedup vs baseline: 1.3224x; 1.2547x over previous
//
#include <hip/hip_runtime.h>
#include <cstdint>
#include <cstddef>

// ---------- common ----------
typedef __bf16 bf16x8 __attribute__((ext_vector_type(8)));
typedef float  f32x4  __attribute__((ext_vector_type(4)));
typedef unsigned short u16x8 __attribute__((ext_vector_type(8)));

__device__ __forceinline__ uint16_t f2bf(float f) {
  uint32_t u = __float_as_uint(f);
  u += 0x7fffu + ((u >> 16) & 1u);          // round-to-nearest-even
  return (uint16_t)(u >> 16);
}
__device__ __forceinline__ float bf2f(uint16_t u) {
  return __uint_as_float((uint32_t)u << 16);
}

__device__ __forceinline__ f32x4 mfma16(bf16x8 a, bf16x8 b, f32x4 c) {
  return __builtin_amdgcn_mfma_f32_16x16x32_bf16(a, b, c, 0, 0, 0);
}

#define GLD_TO_LDS16(gptr, lptr)                                                   \
  __builtin_amdgcn_global_load_lds(                                                \
      (const __attribute__((address_space(1))) void*)(gptr),                       \
      (__attribute__((address_space(3))) void*)(lptr), 16, 0, 0)

// ---------- fused fp32 -> bf16 cast of all 4 tensors ----------
__global__ void cvt_all(const float* __restrict__ q, const float* __restrict__ k,
                        const float* __restrict__ w, const float* __restrict__ wo,
                        uint16_t* __restrict__ Xq, uint16_t* __restrict__ Xk,
                        uint16_t* __restrict__ Wb, uint16_t* __restrict__ Wob) {
  int i = blockIdx.x * blockDim.x + threadIdx.x;
  const float* src;
  uint16_t* dst;
  int off;
  if (i < 1048576)      { src = q;  dst = Xq;  off = i; }
  else if (i < 2097152) { src = k;  dst = Xk;  off = i - 1048576; }
  else if (i < 2883584) { src = w;  dst = Wb;  off = i - 2097152; }
  else                  { src = wo; dst = Wob; off = i - 2883584; }
  float4 v = ((const float4*)src)[off];
  ushort4 o;
  o.x = f2bf(v.x); o.y = f2bf(v.y); o.z = f2bf(v.z); o.w = f2bf(v.w);
  ((ushort4*)dst)[off] = o;
}

// ---------- fused Q + KV projection, 128x128 tiles, grid 768 (3 blk/CU) ----
__global__ __launch_bounds__(256)
void gemm_qkv(const uint16_t* __restrict__ Xq, const uint16_t* __restrict__ Xk,
              const uint16_t* __restrict__ Wb, const float* __restrict__ ipb,
              uint16_t* __restrict__ Qb, uint16_t* __restrict__ Kb,
              uint16_t* __restrict__ Vt) {
  __shared__ __align__(16) uint16_t As[128 * 32];
  __shared__ __align__(16) uint16_t Bs[128 * 32];
  const int tid  = threadIdx.x;
  const int wave = tid >> 6, lane = tid & 63;
  const int quad = lane >> 4, l16 = lane & 15;

  const int bid = blockIdx.x;
  const uint16_t *A, *B;
  const float* bias;
  int bm, bn, mode;
  if (bid < 256) {
    mode = 0; A = Xq; B = Wb; bias = ipb;
    bm = bid >> 3; bn = bid & 7;
  } else {
    mode = 1; A = Xk; B = Wb + (1 << 20); bias = ipb + 1024;
    int t = bid - 256; bm = t >> 4; bn = t & 15;
  }
  const int wm = (wave >> 1) << 6, wn = (wave & 1) << 6;
  const int K = 1024;

  f32x4 acc[4][4] = {};

  for (int k0 = 0; k0 < K; k0 += 32) {
    __syncthreads();
#pragma unroll
    for (int j = 0; j < 2; j++) {
      int c   = wave * 128 + j * 64 + lane;
      int row = c >> 2, kc = c & 3;
      const uint16_t* ga = A + (size_t)(bm * 128 + row) * K + k0 + kc * 8;
      GLD_TO_LDS16(ga, As + (size_t)(wave * 128 + j * 64) * 8);
      const uint16_t* gb = B + (size_t)(bn * 128 + row) * K + k0 + kc * 8;
      GLD_TO_LDS16(gb, Bs + (size_t)(wave * 128 + j * 64) * 8);
    }
    __syncthreads();

    bf16x8 af[4], bfr[4];
#pragma unroll
    for (int i = 0; i < 4; i++) {
      af[i]  = *(const bf16x8*)(As + (wm + i * 16 + l16) * 32 + quad * 8);
      bfr[i] = *(const bf16x8*)(Bs + (wn + i * 16 + l16) * 32 + quad * 8);
    }
#pragma unroll
    for (int mi = 0; mi < 4; mi++)
#pragma unroll
      for (int ni = 0; ni < 4; ni++)
        acc[mi][ni] = mfma16(af[mi], bfr[ni], acc[mi][ni]);
  }

#pragma unroll
  for (int mi = 0; mi < 4; mi++)
#pragma unroll
    for (int ni = 0; ni < 4; ni++)
#pragma unroll
      for (int r = 0; r < 4; r++) {
        int gi = bm * 128 + wm + mi * 16 + quad * 4 + r;  // row = t*4+b
        int gf = bn * 128 + wn + ni * 16 + l16;
        float c = acc[mi][ni][r] + bias[gf];
        if (mode == 0) {
          c *= 0.125f;  // HD^-0.5
          int t = gi >> 2, b = gi & 3, h = gf >> 6, d = gf & 63;
          Qb[((((size_t)b * 16 + h) * 1024 + t) << 6) + d] = f2bf(c);
        } else {
          int s = gi >> 2, b = gi & 3;
          if (gf < 1024) {
            int h = gf >> 6, d = gf & 63;
            Kb[((((size_t)b * 16 + h) * 1024 + s) << 6) + d] = f2bf(c);
          } else {
            int fv = gf - 1024, h = fv >> 6, d = fv & 63;
            Vt[((((size_t)b * 16 + h) * 64 + d) << 10) + s] = f2bf(c);
          }
        }
      }
}

// ---------- out-projection, 64x128 tiles, grid 512 (2 blk/CU) ----------
__global__ __launch_bounds__(256)
void gemm_out(const uint16_t* __restrict__ A, const uint16_t* __restrict__ B,
              const float* __restrict__ bias, float* __restrict__ o32) {
  __shared__ __align__(16) uint16_t As[64 * 32];
  __shared__ __align__(16) uint16_t Bs[128 * 32];
  const int tid  = threadIdx.x;
  const int wave = tid >> 6, lane = tid & 63;
  const int quad = lane >> 4, l16 = lane & 15;
  const int bm = blockIdx.x >> 3, bn = blockIdx.x & 7;  // 64 x 8 tiles
  const int wm = (wave >> 1) << 5, wn = (wave & 1) << 6;
  const int K = 1024;

  f32x4 acc[2][4] = {};

  for (int k0 = 0; k0 < K; k0 += 32) {
    __syncthreads();
    {
      int c   = wave * 64 + lane;       // A: 256 chunks, 1/thread
      int row = c >> 2, kc = c & 3;
      const uint16_t* ga = A + (size_t)(bm * 64 + row) * K + k0 + kc * 8;
      GLD_TO_LDS16(ga, As + (size_t)(wave * 64) * 8);
    }
#pragma unroll
    for (int j = 0; j < 2; j++) {       // B: 512 chunks, 2/thread
      int c   = wave * 128 + j * 64 + lane;
      int row = c >> 2, kc = c & 3;
      const uint16_t* gb = B + (size_t)(bn * 128 + row) * K + k0 + kc * 8;
      GLD_TO_LDS16(gb, Bs + (size_t)(wave * 128 + j * 64) * 8);
    }
    __syncthreads();

    bf16x8 af[2], bfr[4];
#pragma unroll
    for (int i = 0; i < 2; i++)
      af[i] = *(const bf16x8*)(As + (wm + i * 16 + l16) * 32 + quad * 8);
#pragma unroll
    for (int i = 0; i < 4; i++)
      bfr[i] = *(const bf16x8*)(Bs + (wn + i * 16 + l16) * 32 + quad * 8);
#pragma unroll
    for (int mi = 0; mi < 2; mi++)
#pragma unroll
      for (int ni = 0; ni < 4; ni++)
        acc[mi][ni] = mfma16(af[mi], bfr[ni], acc[mi][ni]);
  }

#pragma unroll
  for (int mi = 0; mi < 2; mi++)
#pragma unroll
    for (int ni = 0; ni < 4; ni++)
#pragma unroll
      for (int r = 0; r < 4; r++) {
        int gi = bm * 64 + wm + mi * 16 + quad * 4 + r;
        int gf = bn * 128 + wn + ni * 16 + l16;
        o32[(size_t)gi * 1024 + gf] = acc[mi][ni][r] + bias[gf];
      }
}

// ---------- attention: block = (b, head-group-of-8, t-tile16) ----------
// grid 512 = 4b x 2hg x 64tt, 2 blocks/CU, 8 waves/CU, no spills (cap 256).
// qb (b,h,t,d) pre-scaled; kb (b,h,s,d); vtb (b,h,d,s); hard (b,t,s) fp32
// attn_out (t,b,h*64+d) bf16; hg0 -> avg0 fp32 (plain), hg1 -> part1 bf16.
__global__ __launch_bounds__(256, 2)
void attn_kernel(const uint16_t* __restrict__ qb, const uint16_t* __restrict__ kb,
                 const uint16_t* __restrict__ vtb, const float* __restrict__ hard,
                 uint16_t* __restrict__ attn_out, float* __restrict__ avg0,
                 uint16_t* __restrict__ part1) {
  __shared__ __align__(16) uint16_t P[16 * 1032];  // masked unnormalized exp
  __shared__ float redS[4][16];

  const int bid = blockIdx.x;
  const int b  = bid >> 7;
  const int hg = (bid >> 6) & 1;
  const int t0 = (bid & 63) << 4;
  const int tid = threadIdx.x, wave = tid >> 6, lane = tid & 63;
  const int quad = lane >> 4, l16 = lane & 15;
  const int tl = quad * 4;              // C-frag rows tl..tl+3
  const int sbase = wave * 256 + l16;   // C-frag s column base
  const int so = (wave * 4 + quad) * 64;  // avg ownership: row l16, s [so,so+64)

  // hard mask -> 64-bit register mask, bit n*4+r <-> (t=t0+tl+r, s=sbase+n*16)
  unsigned long long hbits = 0ull;
#pragma unroll
  for (int n = 0; n < 16; n++)
#pragma unroll
    for (int r = 0; r < 4; r++) {
      float hv = hard[(size_t)(b * 1024 + t0 + tl + r) * 1024 + sbase + n * 16];
      if (hv != 0.0f) hbits |= (1ull << (n * 4 + r));
    }

  float avg[64];
#pragma unroll
  for (int j = 0; j < 64; j++) avg[j] = 0.f;

  for (int hh = 0; hh < 8; hh++) {
    const int h = hg * 8 + hh;
    const size_t bh = (size_t)(b * 16 + h);

    // Q A-frags (m = l16, k = quad*8+j)
    const uint16_t* qrow = qb + ((bh << 10) + t0 + l16) * 64;
    bf16x8 aq0 = *(const bf16x8*)(qrow + quad * 8);
    bf16x8 aq1 = *(const bf16x8*)(qrow + 32 + quad * 8);

    // streaming S = QK^T: per n compute -> exp -> sum -> masked-exp to P.
    // No sreg[16] array => no spills. |score| small => exp safe w/o max-sub.
    float sm[4] = {0.f, 0.f, 0.f, 0.f};
#pragma unroll
    for (int n = 0; n < 16; n++) {
      const uint16_t* krow = kb + ((bh << 10) + wave * 256 + n * 16 + l16) * 64;
      bf16x8 bk0 = *(const bf16x8*)(krow + quad * 8);
      bf16x8 bk1 = *(const bf16x8*)(krow + 32 + quad * 8);
      f32x4 c = {};
      c = mfma16(aq0, bk0, c);
      c = mfma16(aq1, bk1, c);
#pragma unroll
      for (int r = 0; r < 4; r++) {
        float e = __expf(c[r]);
        sm[r] += e;
        float em = ((hbits >> (n * 4 + r)) & 1ull) ? e : 0.f;
        P[(tl + r) * 1032 + sbase + n * 16] = f2bf(em);
      }
    }
#pragma unroll
    for (int r = 0; r < 4; r++) {
      float s = sm[r];
#pragma unroll
      for (int off = 1; off < 16; off <<= 1) s += __shfl_xor(s, off);
      if (l16 == 0) redS[wave][tl + r] = s;
    }
    __syncthreads();

    // row 1/sum for PV rows (tl+r) and for this lane's avg row (l16)
    float rlrow[4];
#pragma unroll
    for (int r = 0; r < 4; r++)
      rlrow[r] = 1.0f / (redS[0][tl + r] + redS[1][tl + r] +
                         redS[2][tl + r] + redS[3][tl + r]);
    float rlavg = 1.0f / (redS[0][l16] + redS[1][l16] +
                          redS[2][l16] + redS[3][l16]);

    // head-average accumulation: re-read masked exp from P, contiguous-s
#pragma unroll
    for (int j = 0; j < 8; j++) {
      u16x8 pv = *(const u16x8*)(P + l16 * 1032 + so + j * 8);
#pragma unroll
      for (int e = 0; e < 8; e++)
        avg[j * 8 + e] += bf2f(pv[e]) * rlavg;
    }

    // O = (P @ V) * rl : wave covers d in [wave*16, wave*16+16)
    f32x4 oa[4] = {};
#pragma unroll
    for (int kc = 0; kc < 32; kc++) {
      bf16x8 ap = *(const bf16x8*)(P + l16 * 1032 + kc * 32 + quad * 8);
      bf16x8 bv = *(const bf16x8*)(vtb + ((bh << 6) + wave * 16 + l16) * 1024 +
                                   kc * 32 + quad * 8);
      oa[kc & 3] = mfma16(ap, bv, oa[kc & 3]);
    }
#pragma unroll
    for (int r = 0; r < 4; r++) {
      float o = (oa[0][r] + oa[1][r] + oa[2][r] + oa[3][r]) * rlrow[r];
      attn_out[((size_t)(t0 + tl + r) * 4 + b) * 1024 + h * 64 + wave * 16 + l16] =
          f2bf(o);
    }
    __syncthreads();  // protect P/redS before next head overwrites
  }

  // write this head-group's partial sum: row (b, t0+l16), cols so..so+63
  const size_t rowoff = (size_t)(b * 1024 + t0 + l16) * 1024 + so;
  if (hg == 0) {
    float* dst = avg0 + rowoff;
#pragma unroll
    for (int j = 0; j < 16; j++) {
      float4 v = {avg[j * 4], avg[j * 4 + 1], avg[j * 4 + 2], avg[j * 4 + 3]};
      *(float4*)(dst + j * 4) = v;
    }
  } else {
    uint16_t* dst = part1 + rowoff;
#pragma unroll
    for (int j = 0; j < 8; j++) {
      u16x8 v;
#pragma unroll
      for (int e = 0; e < 8; e++) v[e] = f2bf(avg[j * 8 + e]);
      *(u16x8*)(dst + j * 8) = v;
    }
  }
}

// ---------- combine: avg = (avg0 + part1) / 16, in place on d_out ----------
__global__ void avg_combine(float* __restrict__ avg, const uint16_t* __restrict__ part1) {
  int i = blockIdx.x * blockDim.x + threadIdx.x;  // one float4 per thread
  float4 a = ((const float4*)avg)[i];
  ushort4 p = ((const ushort4*)part1)[i];
  a.x = (a.x + bf2f(p.x)) * 0.0625f;
  a.y = (a.y + bf2f(p.y)) * 0.0625f;
  a.z = (a.z + bf2f(p.z)) * 0.0625f;
  a.w = (a.w + bf2f(p.w)) * 0.0625f;
  ((float4*)avg)[i] = a;
}

// ---------- launch ----------
extern "C" void kernel_launch(void* const* d_in, const int* in_sizes, int n_in,
                              void* d_out, int out_size, void* d_ws, size_t ws_size,
                              hipStream_t stream) {
  const float* query = (const float*)d_in[0];
  const float* key   = (const float*)d_in[1];
  const float* hard  = (const float*)d_in[2];
  const float* ipw   = (const float*)d_in[3];
  const float* ipb   = (const float*)d_in[4];
  const float* opw   = (const float*)d_in[5];
  const float* opb   = (const float*)d_in[6];

  char* ws = (char*)d_ws;
  const size_t MB = 1ull << 20;
  uint16_t* Xq  = (uint16_t*)(ws + 0);        // 8 MB (reused as attn_out)
  uint16_t* Xk  = (uint16_t*)(ws + 8 * MB);   // 8 MB (reused as part1)
  uint16_t* Wb  = (uint16_t*)(ws + 16 * MB);  // 6 MB
  uint16_t* Wob = (uint16_t*)(ws + 22 * MB);  // 2 MB
  uint16_t* Qb  = (uint16_t*)(ws + 24 * MB);  // 8 MB (b,h,t,d)
  uint16_t* Kb  = (uint16_t*)(ws + 32 * MB);  // 8 MB (b,h,s,d)
  uint16_t* Vt  = (uint16_t*)(ws + 40 * MB);  // 8 MB (b,h,d,s)
  uint16_t* AO  = Xq;                         // alias: Xq dead after gemm_qkv
  uint16_t* P1  = Xk;                         // alias: Xk dead after gemm_qkv

  float* out = (float*)d_out;
  float* avg = out + 4194304;

  cvt_all<<<12288, 256, 0, stream>>>(query, key, ipw, opw, Xq, Xk, Wb, Wob);

  // fused Q-proj (256 blocks) + KV-proj (512 blocks)
  gemm_qkv<<<768, 256, 0, stream>>>(Xq, Xk, Wb, ipb, Qb, Kb, Vt);

  // attention: hg0 -> avg (fp32 sums), hg1 -> P1 (bf16 sums)
  attn_kernel<<<512, 256, 0, stream>>>(Qb, Kb, Vt, hard, AO, avg, P1);

  // avg = (avg + P1) / 16
  avg_combine<<<4096, 256, 0, stream>>>(avg, P1);

  // out = AO @ Wo^T + bias (fp32 direct to d_out)
  gemm_out<<<512, 256, 0, stream>>>(AO, Wob, opb, out);
}